// Round 8
// baseline (1028.090 us; speedup 1.0000x reference)
//
#include <hip/hip_runtime.h>

#define N_   128
#define C_   12
#define L_   2048
#define H_   32
#define K_   8
#define CP_  6
#define KW_  9
#define FEAT_ 8192   // D*DIV*2*H*K

// s_buf: [0..3071] padded conv input, then reused as 16x16x17 reduce matrix
#define SBUF_ 4352

template<int DIL, bool GUARD>
__device__ __forceinline__ void conv_phase(const float* __restrict__ s,
                                           const float* __restrict__ wr,
                                           float* __restrict__ cx,
                                           int* __restrict__ cn,
                                           const int tid)
{
    #pragma unroll
    for (int i = 0; i < 8; ++i) {
        const int t = tid + (i << 8);
        // GUARD (df=1, Lout=2047): only t=2047 (tid=255, i=7) is out of range
        if (GUARD && (i == 7) && (tid == 255)) continue;

        float a0 = 0.f, a1 = 0.f, a2 = 0.f, a3 = 0.f,
              a4 = 0.f, a5 = 0.f, a6 = 0.f, a7 = 0.f;
        #pragma unroll
        for (int w = 0; w < KW_; ++w) {
            const float v = s[t + w * DIL];   // lane-stride-1: conflict-free
            a0 = fmaf(v, wr[0 * KW_ + w], a0);
            a1 = fmaf(v, wr[1 * KW_ + w], a1);
            a2 = fmaf(v, wr[2 * KW_ + w], a2);
            a3 = fmaf(v, wr[3 * KW_ + w], a3);
            a4 = fmaf(v, wr[4 * KW_ + w], a4);
            a5 = fmaf(v, wr[5 * KW_ + w], a5);
            a6 = fmaf(v, wr[6 * KW_ + w], a6);
            a7 = fmaf(v, wr[7 * KW_ + w], a7);
        }
        // v_max3/v_min3-fusable trees
        const float mxa = fmaxf(fmaxf(a0, a1), a2);
        const float mxb = fmaxf(fmaxf(a3, a4), a5);
        const float mxc = fmaxf(fmaxf(a6, a7), mxa);
        const float mx  = fmaxf(mxb, mxc);
        const float mna = fminf(fminf(a0, a1), a2);
        const float mnb = fminf(fminf(a3, a4), a5);
        const float mnc = fminf(fminf(a6, a7), mna);
        const float mn  = fminf(mnb, mnc);
        // equality scatter (exact ties across distinct random taps: measure-zero)
        cx[0] += (a0 == mx) ? a0 : 0.f;  cn[0] += (a0 == mn);
        cx[1] += (a1 == mx) ? a1 : 0.f;  cn[1] += (a1 == mn);
        cx[2] += (a2 == mx) ? a2 : 0.f;  cn[2] += (a2 == mn);
        cx[3] += (a3 == mx) ? a3 : 0.f;  cn[3] += (a3 == mn);
        cx[4] += (a4 == mx) ? a4 : 0.f;  cn[4] += (a4 == mn);
        cx[5] += (a5 == mx) ? a5 : 0.f;  cn[5] += (a5 == mn);
        cx[6] += (a6 == mx) ? a6 : 0.f;  cn[6] += (a6 == mn);
        cx[7] += (a7 == mx) ? a7 : 0.f;  cn[7] += (a7 == mn);
    }
}

__global__ __launch_bounds__(256, 8) void hydra_kernel(
    const float* __restrict__ X,   // [N, C, L]
    const float* __restrict__ W,   // [D, DIV, K*H, 1, KW]
    const int*   __restrict__ I,   // [D, DIV, H, CP]
    float* __restrict__ out)       // [N, FEAT]
{
    __shared__ float s_buf[SBUF_];

    const int tid  = threadIdx.x;
    const int b    = blockIdx.x;
    const int h    = b & (H_ - 1);
    const int comb = (b >> 5) & 15;     // di*2 + df
    const int n    = b >> 9;
    const int df   = comb & 1;
    const int di   = comb >> 1;
    const int d    = 1 << di;
    const int Lsrc = L_ - df;           // 2048 or 2047
    const int pad  = 4 * d;

    // ---- zero init, stride-1 (conflict-free) ----
    #pragma unroll
    for (int i = 0; i < 12; ++i) s_buf[tid + i * 256] = 0.0f;

    // block-uniform channel indices (scalarized)
    const int* Ib = I + (comb * H_ + h) * CP_;
    const int c0 = Ib[0], c1 = Ib[1], c2 = Ib[2],
              c3 = Ib[3], c4 = Ib[4], c5 = Ib[5];
    const float* Xn = X + (size_t)n * (C_ * L_);
    const float* x0 = Xn + c0 * L_;
    const float* x1 = Xn + c1 * L_;
    const float* x2 = Xn + c2 * L_;
    const float* x3 = Xn + c3 * L_;
    const float* x4 = Xn + c4 * L_;
    const float* x5 = Xn + c5 * L_;

    // block-uniform weights -> SGPRs
    const float* Wb = W + (size_t)(comb * (K_ * H_) + h * K_) * KW_;
    float wr[K_ * KW_];
    #pragma unroll
    for (int q = 0; q < K_ * KW_; ++q) wr[q] = Wb[q];

    __syncthreads();   // zeros visible

    // ---- staging: coalesced global, stride-1 LDS ----
    for (int t = tid; t < Lsrc; t += 256) {
        float v;
        if (df == 0) {
            v = x0[t] + x1[t] + x2[t] + x3[t] + x4[t] + x5[t];
        } else {
            v = (x0[t + 1] - x0[t]) + (x1[t + 1] - x1[t]) + (x2[t + 1] - x2[t])
              + (x3[t + 1] - x3[t]) + (x4[t + 1] - x4[t]) + (x5[t + 1] - x5[t]);
        }
        s_buf[pad + t] = v;
    }

    __syncthreads();

    // ---- conv + equality-scatter (templated dilation) ----
    float cx[K_] = {0.f, 0.f, 0.f, 0.f, 0.f, 0.f, 0.f, 0.f};
    int   cn[K_] = {0, 0, 0, 0, 0, 0, 0, 0};

    switch (comb) {
        case  0: conv_phase<  1, false>(s_buf, wr, cx, cn, tid); break;
        case  1: conv_phase<  1, true >(s_buf, wr, cx, cn, tid); break;
        case  2: conv_phase<  2, false>(s_buf, wr, cx, cn, tid); break;
        case  3: conv_phase<  2, true >(s_buf, wr, cx, cn, tid); break;
        case  4: conv_phase<  4, false>(s_buf, wr, cx, cn, tid); break;
        case  5: conv_phase<  4, true >(s_buf, wr, cx, cn, tid); break;
        case  6: conv_phase<  8, false>(s_buf, wr, cx, cn, tid); break;
        case  7: conv_phase<  8, true >(s_buf, wr, cx, cn, tid); break;
        case  8: conv_phase< 16, false>(s_buf, wr, cx, cn, tid); break;
        case  9: conv_phase< 16, true >(s_buf, wr, cx, cn, tid); break;
        case 10: conv_phase< 32, false>(s_buf, wr, cx, cn, tid); break;
        case 11: conv_phase< 32, true >(s_buf, wr, cx, cn, tid); break;
        case 12: conv_phase< 64, false>(s_buf, wr, cx, cn, tid); break;
        case 13: conv_phase< 64, true >(s_buf, wr, cx, cn, tid); break;
        case 14: conv_phase<128, false>(s_buf, wr, cx, cn, tid); break;
        default: conv_phase<128, true >(s_buf, wr, cx, cn, tid); break;
    }

    __syncthreads();   // conv done reading s_buf

    // ---- conflict-free reduce matrix ----
    // accumulator r of source thread s lives at s_buf[(r*16 + (s>>4))*17 + (s&15)]
    // write banks: (16r + 17(s>>4) + (s&15)) % 32 -> <=2 lanes/bank (free)
    {
        const int wc = tid >> 4;   // 0..15
        const int wu = tid & 15;   // 0..15
        #pragma unroll
        for (int k = 0; k < K_; ++k) {
            s_buf[((k     ) * 16 + wc) * 17 + wu] = cx[k];
            s_buf[((k + 8 ) * 16 + wc) * 17 + wu] = (float)cn[k];
        }
    }
    __syncthreads();

    {
        const int r = tid >> 4;    // accumulator id 0..15
        const int c = tid & 15;    // chunk id 0..15
        // 16 consecutive words at (r*16+c)*17; bank = 16(r&1)+17c+u -> all 32 banks x2
        const int base = (r * 16 + c) * 17;
        float p = 0.f;
        #pragma unroll
        for (int u = 0; u < 16; ++u)
            p += s_buf[base + u];
        // sum across c (low 4 bits of tid -> within-wave)
        #pragma unroll
        for (int off = 1; off < 16; off <<= 1)
            p += __shfl_xor(p, off, 64);
        if (c == 0) {
            const int s = r >> 3;      // 0 = cmax, 1 = cmin
            const int k = r & 7;
            out[(size_t)n * FEAT_ + (comb * 2 + s) * (H_ * K_) + h * K_ + k] = p;
        }
    }
}

extern "C" void kernel_launch(void* const* d_in, const int* in_sizes, int n_in,
                              void* d_out, int out_size, void* d_ws, size_t ws_size,
                              hipStream_t stream) {
    const float* X = (const float*)d_in[0];
    const float* W = (const float*)d_in[1];
    const int*   I = (const int*)d_in[2];
    float* out = (float*)d_out;

    const int blocks = N_ * 16 * H_;   // 65536: (n, di, df, h)
    hipLaunchKernelGGL(hydra_kernel, dim3(blocks), dim3(256), 0, stream,
                       X, W, I, out);
}

// Round 9
// 639.874 us; speedup vs baseline: 1.6067x; 1.6067x over previous
//
#include <hip/hip_runtime.h>

#define N_   128
#define C_   12
#define L_   2048
#define H_   32
#define K_   8
#define CP_  6
#define KW_  9
#define FEAT_ 8192   // D*DIV*2*H*K

// s_buf: [0..3071] padded conv input, then reused as 16x16x17 reduce matrix
#define SBUF_ 4352

template<int DIL, bool GUARD>
__device__ __forceinline__ void conv_phase(const float* __restrict__ s,
                                           const float* __restrict__ wr,
                                           float* __restrict__ cx,
                                           int* __restrict__ cn,
                                           const int tid)
{
    #pragma unroll
    for (int i = 0; i < 8; ++i) {
        const int t = tid + (i << 8);
        // GUARD (df=1, Lout=2047): only t=2047 (tid=255, i=7) is out of range
        if (GUARD && (i == 7) && (tid == 255)) continue;

        float a0 = 0.f, a1 = 0.f, a2 = 0.f, a3 = 0.f,
              a4 = 0.f, a5 = 0.f, a6 = 0.f, a7 = 0.f;
        #pragma unroll
        for (int w = 0; w < KW_; ++w) {
            const float v = s[t + w * DIL];   // lane-stride-1: conflict-free
            a0 = fmaf(v, wr[0 * KW_ + w], a0);
            a1 = fmaf(v, wr[1 * KW_ + w], a1);
            a2 = fmaf(v, wr[2 * KW_ + w], a2);
            a3 = fmaf(v, wr[3 * KW_ + w], a3);
            a4 = fmaf(v, wr[4 * KW_ + w], a4);
            a5 = fmaf(v, wr[5 * KW_ + w], a5);
            a6 = fmaf(v, wr[6 * KW_ + w], a6);
            a7 = fmaf(v, wr[7 * KW_ + w], a7);
        }
        // v_max3/v_min3-fusable trees
        const float mxa = fmaxf(fmaxf(a0, a1), a2);
        const float mxb = fmaxf(fmaxf(a3, a4), a5);
        const float mxc = fmaxf(fmaxf(a6, a7), mxa);
        const float mx  = fmaxf(mxb, mxc);
        const float mna = fminf(fminf(a0, a1), a2);
        const float mnb = fminf(fminf(a3, a4), a5);
        const float mnc = fminf(fminf(a6, a7), mna);
        const float mn  = fminf(mnb, mnc);
        // equality scatter (exact ties across distinct random taps: measure-zero)
        cx[0] += (a0 == mx) ? a0 : 0.f;  cn[0] += (a0 == mn);
        cx[1] += (a1 == mx) ? a1 : 0.f;  cn[1] += (a1 == mn);
        cx[2] += (a2 == mx) ? a2 : 0.f;  cn[2] += (a2 == mn);
        cx[3] += (a3 == mx) ? a3 : 0.f;  cn[3] += (a3 == mn);
        cx[4] += (a4 == mx) ? a4 : 0.f;  cn[4] += (a4 == mn);
        cx[5] += (a5 == mx) ? a5 : 0.f;  cn[5] += (a5 == mn);
        cx[6] += (a6 == mx) ? a6 : 0.f;  cn[6] += (a6 == mn);
        cx[7] += (a7 == mx) ? a7 : 0.f;  cn[7] += (a7 == mn);
    }
}

__global__ __launch_bounds__(256, 4) void hydra_kernel(
    const float* __restrict__ X,   // [N, C, L]
    const float* __restrict__ W,   // [D, DIV, K*H, 1, KW]
    const int*   __restrict__ I,   // [D, DIV, H, CP]
    float* __restrict__ out)       // [N, FEAT]
{
    __shared__ float s_buf[SBUF_];

    const int tid  = threadIdx.x;
    const int b    = blockIdx.x;
    const int h    = b & (H_ - 1);
    const int comb = (b >> 5) & 15;     // di*2 + df
    const int n    = b >> 9;
    const int df   = comb & 1;
    const int di   = comb >> 1;
    const int d    = 1 << di;
    const int Lsrc = L_ - df;           // 2048 or 2047
    const int pad  = 4 * d;

    // ---- zero init, stride-1 (conflict-free) ----
    #pragma unroll
    for (int i = 0; i < 12; ++i) s_buf[tid + i * 256] = 0.0f;

    // block-uniform channel indices (scalarized)
    const int* Ib = I + (comb * H_ + h) * CP_;
    const int c0 = Ib[0], c1 = Ib[1], c2 = Ib[2],
              c3 = Ib[3], c4 = Ib[4], c5 = Ib[5];
    const float* Xn = X + (size_t)n * (C_ * L_);
    const float* x0 = Xn + c0 * L_;
    const float* x1 = Xn + c1 * L_;
    const float* x2 = Xn + c2 * L_;
    const float* x3 = Xn + c3 * L_;
    const float* x4 = Xn + c4 * L_;
    const float* x5 = Xn + c5 * L_;

    // block-uniform weights -> SGPRs
    const float* Wb = W + (size_t)(comb * (K_ * H_) + h * K_) * KW_;
    float wr[K_ * KW_];
    #pragma unroll
    for (int q = 0; q < K_ * KW_; ++q) wr[q] = Wb[q];

    __syncthreads();   // zeros visible

    // ---- staging: coalesced global, stride-1 LDS ----
    for (int t = tid; t < Lsrc; t += 256) {
        float v;
        if (df == 0) {
            v = x0[t] + x1[t] + x2[t] + x3[t] + x4[t] + x5[t];
        } else {
            v = (x0[t + 1] - x0[t]) + (x1[t + 1] - x1[t]) + (x2[t + 1] - x2[t])
              + (x3[t + 1] - x3[t]) + (x4[t + 1] - x4[t]) + (x5[t + 1] - x5[t]);
        }
        s_buf[pad + t] = v;
    }

    __syncthreads();

    // ---- conv + equality-scatter (templated dilation) ----
    float cx[K_] = {0.f, 0.f, 0.f, 0.f, 0.f, 0.f, 0.f, 0.f};
    int   cn[K_] = {0, 0, 0, 0, 0, 0, 0, 0};

    switch (comb) {
        case  0: conv_phase<  1, false>(s_buf, wr, cx, cn, tid); break;
        case  1: conv_phase<  1, true >(s_buf, wr, cx, cn, tid); break;
        case  2: conv_phase<  2, false>(s_buf, wr, cx, cn, tid); break;
        case  3: conv_phase<  2, true >(s_buf, wr, cx, cn, tid); break;
        case  4: conv_phase<  4, false>(s_buf, wr, cx, cn, tid); break;
        case  5: conv_phase<  4, true >(s_buf, wr, cx, cn, tid); break;
        case  6: conv_phase<  8, false>(s_buf, wr, cx, cn, tid); break;
        case  7: conv_phase<  8, true >(s_buf, wr, cx, cn, tid); break;
        case  8: conv_phase< 16, false>(s_buf, wr, cx, cn, tid); break;
        case  9: conv_phase< 16, true >(s_buf, wr, cx, cn, tid); break;
        case 10: conv_phase< 32, false>(s_buf, wr, cx, cn, tid); break;
        case 11: conv_phase< 32, true >(s_buf, wr, cx, cn, tid); break;
        case 12: conv_phase< 64, false>(s_buf, wr, cx, cn, tid); break;
        case 13: conv_phase< 64, true >(s_buf, wr, cx, cn, tid); break;
        case 14: conv_phase<128, false>(s_buf, wr, cx, cn, tid); break;
        default: conv_phase<128, true >(s_buf, wr, cx, cn, tid); break;
    }

    __syncthreads();   // conv done reading s_buf

    // ---- conflict-free reduce matrix ----
    // accumulator r of source thread s lives at s_buf[(r*16 + (s>>4))*17 + (s&15)]
    // write banks: (16r + 17(s>>4) + (s&15)) % 32 -> <=2 lanes/bank (free)
    {
        const int wc = tid >> 4;   // 0..15
        const int wu = tid & 15;   // 0..15
        #pragma unroll
        for (int k = 0; k < K_; ++k) {
            s_buf[((k     ) * 16 + wc) * 17 + wu] = cx[k];
            s_buf[((k + 8 ) * 16 + wc) * 17 + wu] = (float)cn[k];
        }
    }
    __syncthreads();

    {
        const int r = tid >> 4;    // accumulator id 0..15
        const int c = tid & 15;    // chunk id 0..15
        // 16 consecutive words at (r*16+c)*17; bank = 16(r&1)+17c+u -> all 32 banks x2
        const int base = (r * 16 + c) * 17;
        float p = 0.f;
        #pragma unroll
        for (int u = 0; u < 16; ++u)
            p += s_buf[base + u];
        // sum across c (low 4 bits of tid -> within-wave)
        #pragma unroll
        for (int off = 1; off < 16; off <<= 1)
            p += __shfl_xor(p, off, 64);
        if (c == 0) {
            const int s = r >> 3;      // 0 = cmax, 1 = cmin
            const int k = r & 7;
            out[(size_t)n * FEAT_ + (comb * 2 + s) * (H_ * K_) + h * K_ + k] = p;
        }
    }
}

extern "C" void kernel_launch(void* const* d_in, const int* in_sizes, int n_in,
                              void* d_out, int out_size, void* d_ws, size_t ws_size,
                              hipStream_t stream) {
    const float* X = (const float*)d_in[0];
    const float* W = (const float*)d_in[1];
    const int*   I = (const int*)d_in[2];
    float* out = (float*)d_out;

    const int blocks = N_ * 16 * H_;   // 65536: (n, di, df, h)
    hipLaunchKernelGGL(hydra_kernel, dim3(blocks), dim3(256), 0, stream,
                       X, W, I, out);
}

// Round 10
// 579.444 us; speedup vs baseline: 1.7743x; 1.1043x over previous
//
#include <hip/hip_runtime.h>

#define N_   128
#define C_   12
#define L_   2048
#define H_   32
#define K_   8
#define CP_  6
#define KW_  9
#define FEAT_ 8192   // D*DIV*2*H*K

// s_buf: [0..3071] padded conv input, then reused as 16x16x17 reduce matrix
#define SBUF_ 4352

template<int DIL, bool GUARD>
__device__ __forceinline__ void conv_phase(const float* __restrict__ s,
                                           const float* __restrict__ wr,
                                           float* __restrict__ cx,
                                           int* __restrict__ cn,
                                           const int tid)
{
    #pragma unroll
    for (int g = 0; g < 2; ++g) {
        const int t = g * 1024 + 4 * tid;   // 4 consecutive positions per group

        // register window covering all taps of positions t..t+3 (static-indexed)
        float win[(DIL <= 4) ? (8 * DIL + 4) : 36];
        if constexpr (DIL <= 4) {
            constexpr int NW = 2 * DIL + 1;          // float4 count
            #pragma unroll
            for (int q = 0; q < NW; ++q) {
                const float4 v = *(const float4*)(s + t + 4 * q);  // ds_read_b128
                win[4*q+0] = v.x; win[4*q+1] = v.y;
                win[4*q+2] = v.z; win[4*q+3] = v.w;
            }
        } else {
            #pragma unroll
            for (int w = 0; w < 9; ++w) {            // 9 disjoint aligned runs
                const float4 v = *(const float4*)(s + t + w * DIL);
                win[4*w+0] = v.x; win[4*w+1] = v.y;
                win[4*w+2] = v.z; win[4*w+3] = v.w;
            }
        }

        #pragma unroll
        for (int p = 0; p < 4; ++p) {
            // GUARD (df=1, Lout=2047): only position 2047 (g=1,tid=255,p=3) excluded
            if (GUARD && g == 1 && p == 3 && tid == 255) continue;

            float a0 = 0.f, a1 = 0.f, a2 = 0.f, a3 = 0.f,
                  a4 = 0.f, a5 = 0.f, a6 = 0.f, a7 = 0.f;
            #pragma unroll
            for (int w = 0; w < KW_; ++w) {
                const float v = (DIL <= 4) ? win[p + DIL * w] : win[4 * w + p];
                a0 = fmaf(v, wr[0 * KW_ + w], a0);
                a1 = fmaf(v, wr[1 * KW_ + w], a1);
                a2 = fmaf(v, wr[2 * KW_ + w], a2);
                a3 = fmaf(v, wr[3 * KW_ + w], a3);
                a4 = fmaf(v, wr[4 * KW_ + w], a4);
                a5 = fmaf(v, wr[5 * KW_ + w], a5);
                a6 = fmaf(v, wr[6 * KW_ + w], a6);
                a7 = fmaf(v, wr[7 * KW_ + w], a7);
            }
            // v_max3/v_min3-fusable trees
            const float mxa = fmaxf(fmaxf(a0, a1), a2);
            const float mxb = fmaxf(fmaxf(a3, a4), a5);
            const float mxc = fmaxf(fmaxf(a6, a7), mxa);
            const float mx  = fmaxf(mxb, mxc);
            const float mna = fminf(fminf(a0, a1), a2);
            const float mnb = fminf(fminf(a3, a4), a5);
            const float mnc = fminf(fminf(a6, a7), mna);
            const float mn  = fminf(mnb, mnc);
            // equality scatter (exact ties across distinct random taps: measure-zero)
            cx[0] += (a0 == mx) ? a0 : 0.f;  cn[0] += (a0 == mn);
            cx[1] += (a1 == mx) ? a1 : 0.f;  cn[1] += (a1 == mn);
            cx[2] += (a2 == mx) ? a2 : 0.f;  cn[2] += (a2 == mn);
            cx[3] += (a3 == mx) ? a3 : 0.f;  cn[3] += (a3 == mn);
            cx[4] += (a4 == mx) ? a4 : 0.f;  cn[4] += (a4 == mn);
            cx[5] += (a5 == mx) ? a5 : 0.f;  cn[5] += (a5 == mn);
            cx[6] += (a6 == mx) ? a6 : 0.f;  cn[6] += (a6 == mn);
            cx[7] += (a7 == mx) ? a7 : 0.f;  cn[7] += (a7 == mn);
        }
    }
}

__global__ __launch_bounds__(256, 4) void hydra_kernel(
    const float* __restrict__ X,   // [N, C, L]
    const float* __restrict__ W,   // [D, DIV, K*H, 1, KW]
    const int*   __restrict__ I,   // [D, DIV, H, CP]
    float* __restrict__ out)       // [N, FEAT]
{
    __shared__ __align__(16) float s_buf[SBUF_];

    const int tid  = threadIdx.x;
    const int b    = blockIdx.x;
    const int h    = b & (H_ - 1);
    const int comb = (b >> 5) & 15;     // di*2 + df
    const int n    = b >> 9;
    const int df   = comb & 1;
    const int di   = comb >> 1;
    const int d    = 1 << di;
    const int Lsrc = L_ - df;           // 2048 or 2047
    const int pad  = 4 * d;

    // ---- zero init, stride-1 (conflict-free) ----
    #pragma unroll
    for (int i = 0; i < 12; ++i) s_buf[tid + i * 256] = 0.0f;

    // block-uniform channel indices (scalarized)
    const int* Ib = I + (comb * H_ + h) * CP_;
    const int c0 = Ib[0], c1 = Ib[1], c2 = Ib[2],
              c3 = Ib[3], c4 = Ib[4], c5 = Ib[5];
    const float* Xn = X + (size_t)n * (C_ * L_);
    const float* x0 = Xn + c0 * L_;
    const float* x1 = Xn + c1 * L_;
    const float* x2 = Xn + c2 * L_;
    const float* x3 = Xn + c3 * L_;
    const float* x4 = Xn + c4 * L_;
    const float* x5 = Xn + c5 * L_;

    // block-uniform weights -> SGPRs
    const float* Wb = W + (size_t)(comb * (K_ * H_) + h * K_) * KW_;
    float wr[K_ * KW_];
    #pragma unroll
    for (int q = 0; q < K_ * KW_; ++q) wr[q] = Wb[q];

    __syncthreads();   // zeros visible

    // ---- staging: coalesced global, stride-1 LDS ----
    for (int t = tid; t < Lsrc; t += 256) {
        float v;
        if (df == 0) {
            v = x0[t] + x1[t] + x2[t] + x3[t] + x4[t] + x5[t];
        } else {
            v = (x0[t + 1] - x0[t]) + (x1[t + 1] - x1[t]) + (x2[t + 1] - x2[t])
              + (x3[t + 1] - x3[t]) + (x4[t + 1] - x4[t]) + (x5[t + 1] - x5[t]);
        }
        s_buf[pad + t] = v;
    }

    __syncthreads();

    // ---- conv + equality-scatter (templated dilation, windowed b128 reads) ----
    float cx[K_] = {0.f, 0.f, 0.f, 0.f, 0.f, 0.f, 0.f, 0.f};
    int   cn[K_] = {0, 0, 0, 0, 0, 0, 0, 0};

    switch (comb) {
        case  0: conv_phase<  1, false>(s_buf, wr, cx, cn, tid); break;
        case  1: conv_phase<  1, true >(s_buf, wr, cx, cn, tid); break;
        case  2: conv_phase<  2, false>(s_buf, wr, cx, cn, tid); break;
        case  3: conv_phase<  2, true >(s_buf, wr, cx, cn, tid); break;
        case  4: conv_phase<  4, false>(s_buf, wr, cx, cn, tid); break;
        case  5: conv_phase<  4, true >(s_buf, wr, cx, cn, tid); break;
        case  6: conv_phase<  8, false>(s_buf, wr, cx, cn, tid); break;
        case  7: conv_phase<  8, true >(s_buf, wr, cx, cn, tid); break;
        case  8: conv_phase< 16, false>(s_buf, wr, cx, cn, tid); break;
        case  9: conv_phase< 16, true >(s_buf, wr, cx, cn, tid); break;
        case 10: conv_phase< 32, false>(s_buf, wr, cx, cn, tid); break;
        case 11: conv_phase< 32, true >(s_buf, wr, cx, cn, tid); break;
        case 12: conv_phase< 64, false>(s_buf, wr, cx, cn, tid); break;
        case 13: conv_phase< 64, true >(s_buf, wr, cx, cn, tid); break;
        case 14: conv_phase<128, false>(s_buf, wr, cx, cn, tid); break;
        default: conv_phase<128, true >(s_buf, wr, cx, cn, tid); break;
    }

    __syncthreads();   // conv done reading s_buf

    // ---- conflict-free reduce matrix ----
    // accumulator r of source thread s lives at s_buf[(r*16 + (s>>4))*17 + (s&15)]
    {
        const int wc = tid >> 4;   // 0..15
        const int wu = tid & 15;   // 0..15
        #pragma unroll
        for (int k = 0; k < K_; ++k) {
            s_buf[((k     ) * 16 + wc) * 17 + wu] = cx[k];
            s_buf[((k + 8 ) * 16 + wc) * 17 + wu] = (float)cn[k];
        }
    }
    __syncthreads();

    {
        const int r = tid >> 4;    // accumulator id 0..15
        const int c = tid & 15;    // chunk id 0..15
        const int base = (r * 16 + c) * 17;
        float p = 0.f;
        #pragma unroll
        for (int u = 0; u < 16; ++u)
            p += s_buf[base + u];
        #pragma unroll
        for (int off = 1; off < 16; off <<= 1)
            p += __shfl_xor(p, off, 64);
        if (c == 0) {
            const int s = r >> 3;      // 0 = cmax, 1 = cmin
            const int k = r & 7;
            out[(size_t)n * FEAT_ + (comb * 2 + s) * (H_ * K_) + h * K_ + k] = p;
        }
    }
}

extern "C" void kernel_launch(void* const* d_in, const int* in_sizes, int n_in,
                              void* d_out, int out_size, void* d_ws, size_t ws_size,
                              hipStream_t stream) {
    const float* X = (const float*)d_in[0];
    const float* W = (const float*)d_in[1];
    const int*   I = (const int*)d_in[2];
    float* out = (float*)d_out;

    const int blocks = N_ * 16 * H_;   // 65536: (n, di, df, h)
    hipLaunchKernelGGL(hydra_kernel, dim3(blocks), dim3(256), 0, stream,
                       X, W, I, out);
}

// Round 11
// 567.771 us; speedup vs baseline: 1.8107x; 1.0206x over previous
//
#include <hip/hip_runtime.h>

#define N_   128
#define C_   12
#define L_   2048
#define H_   32
#define K_   8
#define CP_  6
#define KW_  9
#define FEAT_ 8192   // D*DIV*2*H*K

// s_buf: [0..3071] padded conv input, then reused as 16x16x17 reduce matrix
#define SBUF_ 4352

template<int DIL, bool GUARD>
__device__ __forceinline__ void conv_phase(const float* __restrict__ s,
                                           const float* __restrict__ wr,
                                           float* __restrict__ cx,
                                           int* __restrict__ cn,
                                           const int tid)
{
    #pragma unroll
    for (int g = 0; g < 2; ++g) {
        const int t = g * 1024 + 4 * tid;   // 4 consecutive positions per group

        // register window covering all taps of positions t..t+3 (static-indexed)
        float win[(DIL <= 4) ? (8 * DIL + 4) : 36];
        if constexpr (DIL <= 4) {
            constexpr int NW = 2 * DIL + 1;          // float4 count
            #pragma unroll
            for (int q = 0; q < NW; ++q) {
                const float4 v = *(const float4*)(s + t + 4 * q);  // ds_read_b128
                win[4*q+0] = v.x; win[4*q+1] = v.y;
                win[4*q+2] = v.z; win[4*q+3] = v.w;
            }
        } else {
            #pragma unroll
            for (int w = 0; w < 9; ++w) {            // 9 disjoint aligned runs
                const float4 v = *(const float4*)(s + t + w * DIL);
                win[4*w+0] = v.x; win[4*w+1] = v.y;
                win[4*w+2] = v.z; win[4*w+3] = v.w;
            }
        }

        #pragma unroll
        for (int p = 0; p < 4; ++p) {
            // GUARD (df=1, Lout=2047): only position 2047 (g=1,tid=255,p=3) excluded
            if (GUARD && g == 1 && p == 3 && tid == 255) continue;

            float a0 = 0.f, a1 = 0.f, a2 = 0.f, a3 = 0.f,
                  a4 = 0.f, a5 = 0.f, a6 = 0.f, a7 = 0.f;
            #pragma unroll
            for (int w = 0; w < KW_; ++w) {
                const float v = (DIL <= 4) ? win[p + DIL * w] : win[4 * w + p];
                a0 = fmaf(v, wr[0 * KW_ + w], a0);
                a1 = fmaf(v, wr[1 * KW_ + w], a1);
                a2 = fmaf(v, wr[2 * KW_ + w], a2);
                a3 = fmaf(v, wr[3 * KW_ + w], a3);
                a4 = fmaf(v, wr[4 * KW_ + w], a4);
                a5 = fmaf(v, wr[5 * KW_ + w], a5);
                a6 = fmaf(v, wr[6 * KW_ + w], a6);
                a7 = fmaf(v, wr[7 * KW_ + w], a7);
            }
            // v_max3/v_min3-fusable trees
            const float mxa = fmaxf(fmaxf(a0, a1), a2);
            const float mxb = fmaxf(fmaxf(a3, a4), a5);
            const float mxc = fmaxf(fmaxf(a6, a7), mxa);
            const float mx  = fmaxf(mxb, mxc);
            const float mna = fminf(fminf(a0, a1), a2);
            const float mnb = fminf(fminf(a3, a4), a5);
            const float mnc = fminf(fminf(a6, a7), mna);
            const float mn  = fminf(mnb, mnc);
            // equality scatter (exact ties across distinct random taps: measure-zero)
            cx[0] += (a0 == mx) ? a0 : 0.f;  cn[0] += (a0 == mn);
            cx[1] += (a1 == mx) ? a1 : 0.f;  cn[1] += (a1 == mn);
            cx[2] += (a2 == mx) ? a2 : 0.f;  cn[2] += (a2 == mn);
            cx[3] += (a3 == mx) ? a3 : 0.f;  cn[3] += (a3 == mn);
            cx[4] += (a4 == mx) ? a4 : 0.f;  cn[4] += (a4 == mn);
            cx[5] += (a5 == mx) ? a5 : 0.f;  cn[5] += (a5 == mn);
            cx[6] += (a6 == mx) ? a6 : 0.f;  cn[6] += (a6 == mn);
            cx[7] += (a7 == mx) ? a7 : 0.f;  cn[7] += (a7 == mn);
        }
    }
}

__global__ __launch_bounds__(256, 4) void hydra_kernel(
    const float* __restrict__ X,   // [N, C, L]
    const float* __restrict__ W,   // [D, DIV, K*H, 1, KW]
    const int*   __restrict__ I,   // [D, DIV, H, CP]
    float* __restrict__ out)       // [N, FEAT]
{
    __shared__ __align__(16) float s_buf[SBUF_];

    const int tid   = threadIdx.x;
    // ---- XCD-aware swizzle (T1): XCD k = blockIdx%8 owns n in [16k, 16k+16) ----
    // X per n = 98 KB -> L2-resident per XCD instead of 12.6 MB thrash to L3.
    const int b_raw = blockIdx.x;
    const int xcd   = b_raw & 7;
    const int sub   = b_raw >> 3;          // 0..8191
    const int n     = xcd * 16 + (sub >> 9);
    const int rem   = sub & 511;
    const int comb  = rem >> 5;            // di*2 + df
    const int h     = rem & 31;

    const int df   = comb & 1;
    const int di   = comb >> 1;
    const int d    = 1 << di;
    const int Lsrc = L_ - df;              // 2048 or 2047
    const int pad  = 4 * d;

    // ---- zero init, stride-1 (conflict-free) ----
    #pragma unroll
    for (int i = 0; i < 12; ++i) s_buf[tid + i * 256] = 0.0f;

    // block-uniform channel indices (scalarized)
    const int* Ib = I + (comb * H_ + h) * CP_;
    const int c0 = Ib[0], c1 = Ib[1], c2 = Ib[2],
              c3 = Ib[3], c4 = Ib[4], c5 = Ib[5];
    const float* Xn = X + (size_t)n * (C_ * L_);
    const float* x0 = Xn + c0 * L_;
    const float* x1 = Xn + c1 * L_;
    const float* x2 = Xn + c2 * L_;
    const float* x3 = Xn + c3 * L_;
    const float* x4 = Xn + c4 * L_;
    const float* x5 = Xn + c5 * L_;

    // block-uniform weights -> SGPRs
    const float* Wb = W + (size_t)(comb * (K_ * H_) + h * K_) * KW_;
    float wr[K_ * KW_];
    #pragma unroll
    for (int q = 0; q < K_ * KW_; ++q) wr[q] = Wb[q];

    __syncthreads();   // zeros visible

    // ---- staging: coalesced global, stride-1 LDS ----
    for (int t = tid; t < Lsrc; t += 256) {
        float v;
        if (df == 0) {
            v = x0[t] + x1[t] + x2[t] + x3[t] + x4[t] + x5[t];
        } else {
            v = (x0[t + 1] - x0[t]) + (x1[t + 1] - x1[t]) + (x2[t + 1] - x2[t])
              + (x3[t + 1] - x3[t]) + (x4[t + 1] - x4[t]) + (x5[t + 1] - x5[t]);
        }
        s_buf[pad + t] = v;
    }

    __syncthreads();

    // ---- conv + equality-scatter (templated dilation, windowed b128 reads) ----
    float cx[K_] = {0.f, 0.f, 0.f, 0.f, 0.f, 0.f, 0.f, 0.f};
    int   cn[K_] = {0, 0, 0, 0, 0, 0, 0, 0};

    switch (comb) {
        case  0: conv_phase<  1, false>(s_buf, wr, cx, cn, tid); break;
        case  1: conv_phase<  1, true >(s_buf, wr, cx, cn, tid); break;
        case  2: conv_phase<  2, false>(s_buf, wr, cx, cn, tid); break;
        case  3: conv_phase<  2, true >(s_buf, wr, cx, cn, tid); break;
        case  4: conv_phase<  4, false>(s_buf, wr, cx, cn, tid); break;
        case  5: conv_phase<  4, true >(s_buf, wr, cx, cn, tid); break;
        case  6: conv_phase<  8, false>(s_buf, wr, cx, cn, tid); break;
        case  7: conv_phase<  8, true >(s_buf, wr, cx, cn, tid); break;
        case  8: conv_phase< 16, false>(s_buf, wr, cx, cn, tid); break;
        case  9: conv_phase< 16, true >(s_buf, wr, cx, cn, tid); break;
        case 10: conv_phase< 32, false>(s_buf, wr, cx, cn, tid); break;
        case 11: conv_phase< 32, true >(s_buf, wr, cx, cn, tid); break;
        case 12: conv_phase< 64, false>(s_buf, wr, cx, cn, tid); break;
        case 13: conv_phase< 64, true >(s_buf, wr, cx, cn, tid); break;
        case 14: conv_phase<128, false>(s_buf, wr, cx, cn, tid); break;
        default: conv_phase<128, true >(s_buf, wr, cx, cn, tid); break;
    }

    __syncthreads();   // conv done reading s_buf

    // ---- conflict-free reduce matrix ----
    // accumulator r of source thread s lives at s_buf[(r*16 + (s>>4))*17 + (s&15)]
    {
        const int wc = tid >> 4;   // 0..15
        const int wu = tid & 15;   // 0..15
        #pragma unroll
        for (int k = 0; k < K_; ++k) {
            s_buf[((k     ) * 16 + wc) * 17 + wu] = cx[k];
            s_buf[((k + 8 ) * 16 + wc) * 17 + wu] = (float)cn[k];
        }
    }
    __syncthreads();

    {
        const int r = tid >> 4;    // accumulator id 0..15
        const int c = tid & 15;    // chunk id 0..15
        const int base = (r * 16 + c) * 17;
        float p = 0.f;
        #pragma unroll
        for (int u = 0; u < 16; ++u)
            p += s_buf[base + u];
        #pragma unroll
        for (int off = 1; off < 16; off <<= 1)
            p += __shfl_xor(p, off, 64);
        if (c == 0) {
            const int s = r >> 3;      // 0 = cmax, 1 = cmin
            const int k = r & 7;
            out[(size_t)n * FEAT_ + (comb * 2 + s) * (H_ * K_) + h * K_ + k] = p;
        }
    }
}

extern "C" void kernel_launch(void* const* d_in, const int* in_sizes, int n_in,
                              void* d_out, int out_size, void* d_ws, size_t ws_size,
                              hipStream_t stream) {
    const float* X = (const float*)d_in[0];
    const float* W = (const float*)d_in[1];
    const int*   I = (const int*)d_in[2];
    float* out = (float*)d_out;

    const int blocks = N_ * 16 * H_;   // 65536: (n, di, df, h)
    hipLaunchKernelGGL(hydra_kernel, dim3(blocks), dim3(256), 0, stream,
                       X, W, I, out);
}

// Round 13
// 514.318 us; speedup vs baseline: 1.9989x; 1.1039x over previous
//
#include <hip/hip_runtime.h>

#define N_   128
#define C_   12
#define L_   2048
#define H_   32
#define K_   8
#define CP_  6
#define KW_  9
#define FEAT_ 8192   // D*DIV*2*H*K

// s_buf: [0..3071] padded conv input, then reused as 16x16x17 reduce matrix
#define SBUF_ 4352

template<int DIL, bool GUARD>
__device__ __forceinline__ void conv_phase(const float* __restrict__ s,
                                           const float* __restrict__ wr,
                                           float* __restrict__ cx,
                                           int* __restrict__ cn,
                                           const int tid)
{
    #pragma unroll
    for (int g = 0; g < 2; ++g) {
        const int t = g * 1024 + 4 * tid;   // 4 consecutive positions per group

        // register window covering all taps of positions t..t+3 (static-indexed)
        float win[(DIL <= 4) ? (8 * DIL + 4) : 36];
        if constexpr (DIL <= 4) {
            constexpr int NW = 2 * DIL + 1;          // float4 count
            #pragma unroll
            for (int q = 0; q < NW; ++q) {
                const float4 v = *(const float4*)(s + t + 4 * q);  // ds_read_b128
                win[4*q+0] = v.x; win[4*q+1] = v.y;
                win[4*q+2] = v.z; win[4*q+3] = v.w;
            }
        } else {
            #pragma unroll
            for (int w = 0; w < 9; ++w) {            // 9 disjoint aligned runs
                const float4 v = *(const float4*)(s + t + w * DIL);
                win[4*w+0] = v.x; win[4*w+1] = v.y;
                win[4*w+2] = v.z; win[4*w+3] = v.w;
            }
        }

        #pragma unroll
        for (int p = 0; p < 4; ++p) {
            // GUARD (df=1, Lout=2047): only position 2047 (g=1,tid=255,p=3) excluded
            if (GUARD && g == 1 && p == 3 && tid == 255) continue;

            float a0 = 0.f, a1 = 0.f, a2 = 0.f, a3 = 0.f,
                  a4 = 0.f, a5 = 0.f, a6 = 0.f, a7 = 0.f;
            #pragma unroll
            for (int w = 0; w < KW_; ++w) {
                const float v = (DIL <= 4) ? win[p + DIL * w] : win[4 * w + p];
                a0 = fmaf(v, wr[0 * KW_ + w], a0);
                a1 = fmaf(v, wr[1 * KW_ + w], a1);
                a2 = fmaf(v, wr[2 * KW_ + w], a2);
                a3 = fmaf(v, wr[3 * KW_ + w], a3);
                a4 = fmaf(v, wr[4 * KW_ + w], a4);
                a5 = fmaf(v, wr[5 * KW_ + w], a5);
                a6 = fmaf(v, wr[6 * KW_ + w], a6);
                a7 = fmaf(v, wr[7 * KW_ + w], a7);
            }
            // v_max3/v_min3-fusable trees
            const float mxa = fmaxf(fmaxf(a0, a1), a2);
            const float mxb = fmaxf(fmaxf(a3, a4), a5);
            const float mxc = fmaxf(fmaxf(a6, a7), mxa);
            const float mx  = fmaxf(mxb, mxc);
            const float mna = fminf(fminf(a0, a1), a2);
            const float mnb = fminf(fminf(a3, a4), a5);
            const float mnc = fminf(fminf(a6, a7), mna);
            const float mn  = fminf(mnb, mnc);
            // equality scatter (exact ties across distinct random taps: measure-zero)
            cx[0] += (a0 == mx) ? a0 : 0.f;  cn[0] += (a0 == mn);
            cx[1] += (a1 == mx) ? a1 : 0.f;  cn[1] += (a1 == mn);
            cx[2] += (a2 == mx) ? a2 : 0.f;  cn[2] += (a2 == mn);
            cx[3] += (a3 == mx) ? a3 : 0.f;  cn[3] += (a3 == mn);
            cx[4] += (a4 == mx) ? a4 : 0.f;  cn[4] += (a4 == mn);
            cx[5] += (a5 == mx) ? a5 : 0.f;  cn[5] += (a5 == mn);
            cx[6] += (a6 == mx) ? a6 : 0.f;  cn[6] += (a6 == mn);
            cx[7] += (a7 == mx) ? a7 : 0.f;  cn[7] += (a7 == mn);
        }
    }
}

__global__ __launch_bounds__(256, 4) void hydra_kernel(
    const float* __restrict__ X,   // [N, C, L]
    const float* __restrict__ W,   // [D, DIV, K*H, 1, KW]
    const int*   __restrict__ I,   // [D, DIV, H, CP]
    float* __restrict__ out)       // [N, FEAT]
{
    __shared__ __align__(16) float s_buf[SBUF_];

    const int tid   = threadIdx.x;
    // ---- XCD-aware swizzle (T1): XCD k = blockIdx%8 owns n in [16k, 16k+16) ----
    const int b_raw = blockIdx.x;
    const int xcd   = b_raw & 7;
    const int sub   = b_raw >> 3;          // 0..8191
    const int n     = xcd * 16 + (sub >> 9);
    const int rem   = sub & 511;
    const int comb  = rem >> 5;            // di*2 + df
    const int h     = rem & 31;

    const int df   = comb & 1;
    const int di   = comb >> 1;
    const int d    = 1 << di;
    const int pad  = 4 * d;

    // ---- zero init, stride-1 (conflict-free) ----
    #pragma unroll
    for (int i = 0; i < 12; ++i) s_buf[tid + i * 256] = 0.0f;

    // block-uniform channel indices (scalarized)
    const int* Ib = I + (comb * H_ + h) * CP_;
    const int c0 = Ib[0], c1 = Ib[1], c2 = Ib[2],
              c3 = Ib[3], c4 = Ib[4], c5 = Ib[5];
    const float* Xn = X + (size_t)n * (C_ * L_);
    const float* xp0 = Xn + c0 * L_;
    const float* xp1 = Xn + c1 * L_;
    const float* xp2 = Xn + c2 * L_;
    const float* xp3 = Xn + c3 * L_;
    const float* xp4 = Xn + c4 * L_;
    const float* xp5 = Xn + c5 * L_;

    // block-uniform weights -> SGPRs
    const float* Wb = W + (size_t)(comb * (K_ * H_) + h * K_) * KW_;
    float wr[K_ * KW_];
    #pragma unroll
    for (int q = 0; q < K_ * KW_; ++q) wr[q] = Wb[q];

    __syncthreads();   // zeros visible

    // ---- staging: 48 independent loads issued as one burst (latency-batched) ----
    // Stage raw channel-sum S[t] for t in [0,2048) regardless of df.
    {
        float l0[8], l1[8], l2[8], l3[8], l4[8], l5[8];
        #pragma unroll
        for (int i = 0; i < 8; ++i) {
            const int t = tid + i * 256;
            l0[i] = xp0[t]; l1[i] = xp1[t]; l2[i] = xp2[t];
            l3[i] = xp3[t]; l4[i] = xp4[t]; l5[i] = xp5[t];
        }
        #pragma unroll
        for (int i = 0; i < 8; ++i) {
            const int t = tid + i * 256;
            s_buf[pad + t] = ((l0[i] + l1[i]) + (l2[i] + l3[i])) + (l4[i] + l5[i]);
        }
    }
    __syncthreads();

    // ---- df=1: in-place diff pass, d[t] = S[t+1]-S[t] (== sum of channel diffs) ----
    if (df == 1) {
        float dv[8];
        #pragma unroll
        for (int i = 0; i < 8; ++i) {
            const int t = tid + i * 256;
            dv[i] = s_buf[pad + t + 1] - s_buf[pad + t];   // pad+2048 is zero region
        }
        __syncthreads();
        #pragma unroll
        for (int i = 0; i < 8; ++i) {
            const int t = tid + i * 256;
            s_buf[pad + t] = (i == 7 && tid == 255) ? 0.0f : dv[i];  // t=2047 not in Lsrc
        }
        __syncthreads();
    }

    // ---- conv + equality-scatter (templated dilation, windowed b128 reads) ----
    float cx[K_] = {0.f, 0.f, 0.f, 0.f, 0.f, 0.f, 0.f, 0.f};
    int   cn[K_] = {0, 0, 0, 0, 0, 0, 0, 0};

    switch (comb) {
        case  0: conv_phase<  1, false>(s_buf, wr, cx, cn, tid); break;
        case  1: conv_phase<  1, true >(s_buf, wr, cx, cn, tid); break;
        case  2: conv_phase<  2, false>(s_buf, wr, cx, cn, tid); break;
        case  3: conv_phase<  2, true >(s_buf, wr, cx, cn, tid); break;
        case  4: conv_phase<  4, false>(s_buf, wr, cx, cn, tid); break;
        case  5: conv_phase<  4, true >(s_buf, wr, cx, cn, tid); break;
        case  6: conv_phase<  8, false>(s_buf, wr, cx, cn, tid); break;
        case  7: conv_phase<  8, true >(s_buf, wr, cx, cn, tid); break;
        case  8: conv_phase< 16, false>(s_buf, wr, cx, cn, tid); break;
        case  9: conv_phase< 16, true >(s_buf, wr, cx, cn, tid); break;
        case 10: conv_phase< 32, false>(s_buf, wr, cx, cn, tid); break;
        case 11: conv_phase< 32, true >(s_buf, wr, cx, cn, tid); break;
        case 12: conv_phase< 64, false>(s_buf, wr, cx, cn, tid); break;
        case 13: conv_phase< 64, true >(s_buf, wr, cx, cn, tid); break;
        case 14: conv_phase<128, false>(s_buf, wr, cx, cn, tid); break;
        default: conv_phase<128, true >(s_buf, wr, cx, cn, tid); break;
    }

    __syncthreads();   // conv done reading s_buf

    // ---- conflict-free reduce matrix ----
    // accumulator r of source thread s lives at s_buf[(r*16 + (s>>4))*17 + (s&15)]
    {
        const int wc = tid >> 4;   // 0..15
        const int wu = tid & 15;   // 0..15
        #pragma unroll
        for (int k = 0; k < K_; ++k) {
            s_buf[((k     ) * 16 + wc) * 17 + wu] = cx[k];
            s_buf[((k + 8 ) * 16 + wc) * 17 + wu] = (float)cn[k];
        }
    }
    __syncthreads();

    {
        const int r = tid >> 4;    // accumulator id 0..15
        const int c = tid & 15;    // chunk id 0..15
        const int base = (r * 16 + c) * 17;
        float p = 0.f;
        #pragma unroll
        for (int u = 0; u < 16; ++u)
            p += s_buf[base + u];
        #pragma unroll
        for (int off = 1; off < 16; off <<= 1)
            p += __shfl_xor(p, off, 64);
        if (c == 0) {
            const int s = r >> 3;      // 0 = cmax, 1 = cmin
            const int k = r & 7;
            out[(size_t)n * FEAT_ + (comb * 2 + s) * (H_ * K_) + h * K_ + k] = p;
        }
    }
}

extern "C" void kernel_launch(void* const* d_in, const int* in_sizes, int n_in,
                              void* d_out, int out_size, void* d_ws, size_t ws_size,
                              hipStream_t stream) {
    const float* X = (const float*)d_in[0];
    const float* W = (const float*)d_in[1];
    const int*   I = (const int*)d_in[2];
    float* out = (float*)d_out;

    const int blocks = N_ * 16 * H_;   // 65536: (n, di, df, h)
    hipLaunchKernelGGL(hydra_kernel, dim3(blocks), dim3(256), 0, stream,
                       X, W, I, out);
}

// Round 14
// 407.811 us; speedup vs baseline: 2.5210x; 1.2612x over previous
//
#include <hip/hip_runtime.h>

#define N_   128
#define C_   12
#define L_   2048
#define H_   32
#define K_   8
#define CP_  6
#define KW_  9
#define FEAT_ 8192   // D*DIV*2*H*K

// s_buf: [0..3071] padded conv input, then reused as 16x16x17 reduce matrix
#define SBUF_ 4352

template<int DIL, bool GUARD>
__device__ __forceinline__ void conv_phase(const float* __restrict__ s,
                                           const float* __restrict__ wr,
                                           float* __restrict__ cx,
                                           int* __restrict__ cn,
                                           const int tid)
{
    if constexpr (DIL == 1) {
        // sliding 12-float window, 2 groups of 4 consecutive positions
        #pragma unroll
        for (int g = 0; g < 2; ++g) {
            const int t = g * 1024 + 4 * tid;
            float win[12];
            #pragma unroll
            for (int q = 0; q < 3; ++q) {
                const float4 v = *(const float4*)(s + t + 4 * q);  // ds_read_b128
                win[4*q+0] = v.x; win[4*q+1] = v.y;
                win[4*q+2] = v.z; win[4*q+3] = v.w;
            }
            #pragma unroll
            for (int p = 0; p < 4; ++p) {
                if (GUARD && g == 1 && p == 3 && tid == 255) continue;  // pos 2047
                float a0 = 0.f, a1 = 0.f, a2 = 0.f, a3 = 0.f,
                      a4 = 0.f, a5 = 0.f, a6 = 0.f, a7 = 0.f;
                #pragma unroll
                for (int w = 0; w < KW_; ++w) {
                    const float v = win[p + w];
                    a0 = fmaf(v, wr[0 * KW_ + w], a0);
                    a1 = fmaf(v, wr[1 * KW_ + w], a1);
                    a2 = fmaf(v, wr[2 * KW_ + w], a2);
                    a3 = fmaf(v, wr[3 * KW_ + w], a3);
                    a4 = fmaf(v, wr[4 * KW_ + w], a4);
                    a5 = fmaf(v, wr[5 * KW_ + w], a5);
                    a6 = fmaf(v, wr[6 * KW_ + w], a6);
                    a7 = fmaf(v, wr[7 * KW_ + w], a7);
                }
                const float mxa = fmaxf(fmaxf(a0, a1), a2);
                const float mxb = fmaxf(fmaxf(a3, a4), a5);
                const float mxc = fmaxf(fmaxf(a6, a7), mxa);
                const float mx  = fmaxf(mxb, mxc);
                const float mna = fminf(fminf(a0, a1), a2);
                const float mnb = fminf(fminf(a3, a4), a5);
                const float mnc = fminf(fminf(a6, a7), mna);
                const float mn  = fminf(mnb, mnc);
                cx[0] += (a0 == mx) ? a0 : 0.f;  cn[0] += (a0 == mn);
                cx[1] += (a1 == mx) ? a1 : 0.f;  cn[1] += (a1 == mn);
                cx[2] += (a2 == mx) ? a2 : 0.f;  cn[2] += (a2 == mn);
                cx[3] += (a3 == mx) ? a3 : 0.f;  cn[3] += (a3 == mn);
                cx[4] += (a4 == mx) ? a4 : 0.f;  cn[4] += (a4 == mn);
                cx[5] += (a5 == mx) ? a5 : 0.f;  cn[5] += (a5 == mn);
                cx[6] += (a6 == mx) ? a6 : 0.f;  cn[6] += (a6 == mn);
                cx[7] += (a7 == mx) ? a7 : 0.f;  cn[7] += (a7 == mn);
            }
        }
    } else {
        // 4 subgroups x 2 consecutive positions; 9 float2 window (18 regs)
        #pragma unroll
        for (int g = 0; g < 4; ++g) {
            const int t = g * 512 + 2 * tid;
            float2 wv[9];
            #pragma unroll
            for (int w = 0; w < KW_; ++w)
                wv[w] = *(const float2*)(s + t + w * DIL);   // ds_read_b64
            #pragma unroll
            for (int p = 0; p < 2; ++p) {
                if (GUARD && g == 3 && p == 1 && tid == 255) continue;  // pos 2047
                float a0 = 0.f, a1 = 0.f, a2 = 0.f, a3 = 0.f,
                      a4 = 0.f, a5 = 0.f, a6 = 0.f, a7 = 0.f;
                #pragma unroll
                for (int w = 0; w < KW_; ++w) {
                    const float v = p ? wv[w].y : wv[w].x;
                    a0 = fmaf(v, wr[0 * KW_ + w], a0);
                    a1 = fmaf(v, wr[1 * KW_ + w], a1);
                    a2 = fmaf(v, wr[2 * KW_ + w], a2);
                    a3 = fmaf(v, wr[3 * KW_ + w], a3);
                    a4 = fmaf(v, wr[4 * KW_ + w], a4);
                    a5 = fmaf(v, wr[5 * KW_ + w], a5);
                    a6 = fmaf(v, wr[6 * KW_ + w], a6);
                    a7 = fmaf(v, wr[7 * KW_ + w], a7);
                }
                const float mxa = fmaxf(fmaxf(a0, a1), a2);
                const float mxb = fmaxf(fmaxf(a3, a4), a5);
                const float mxc = fmaxf(fmaxf(a6, a7), mxa);
                const float mx  = fmaxf(mxb, mxc);
                const float mna = fminf(fminf(a0, a1), a2);
                const float mnb = fminf(fminf(a3, a4), a5);
                const float mnc = fminf(fminf(a6, a7), mna);
                const float mn  = fminf(mnb, mnc);
                cx[0] += (a0 == mx) ? a0 : 0.f;  cn[0] += (a0 == mn);
                cx[1] += (a1 == mx) ? a1 : 0.f;  cn[1] += (a1 == mn);
                cx[2] += (a2 == mx) ? a2 : 0.f;  cn[2] += (a2 == mn);
                cx[3] += (a3 == mx) ? a3 : 0.f;  cn[3] += (a3 == mn);
                cx[4] += (a4 == mx) ? a4 : 0.f;  cn[4] += (a4 == mn);
                cx[5] += (a5 == mx) ? a5 : 0.f;  cn[5] += (a5 == mn);
                cx[6] += (a6 == mx) ? a6 : 0.f;  cn[6] += (a6 == mn);
                cx[7] += (a7 == mx) ? a7 : 0.f;  cn[7] += (a7 == mn);
            }
        }
    }
}

__global__ __launch_bounds__(256, 4) void hydra_kernel(
    const float* __restrict__ X,   // [N, C, L]
    const float* __restrict__ W,   // [D, DIV, K*H, 1, KW]
    const int*   __restrict__ I,   // [D, DIV, H, CP]
    float* __restrict__ out)       // [N, FEAT]
{
    __shared__ __align__(16) float s_buf[SBUF_];

    const int tid   = threadIdx.x;
    // ---- XCD-aware swizzle (T1): XCD k = blockIdx%8 owns n in [16k, 16k+16) ----
    const int b_raw = blockIdx.x;
    const int xcd   = b_raw & 7;
    const int sub   = b_raw >> 3;          // 0..8191
    const int n     = xcd * 16 + (sub >> 9);
    const int rem   = sub & 511;
    const int comb  = rem >> 5;            // di*2 + df
    const int h     = rem & 31;

    const int df   = comb & 1;
    const int di   = comb >> 1;
    const int d    = 1 << di;
    const int pad  = 4 * d;

    // ---- zero init, stride-1 (conflict-free) ----
    #pragma unroll
    for (int i = 0; i < 12; ++i) s_buf[tid + i * 256] = 0.0f;

    // block-uniform channel indices (scalarized)
    const int* Ib = I + (comb * H_ + h) * CP_;
    const int c0 = Ib[0], c1 = Ib[1], c2 = Ib[2],
              c3 = Ib[3], c4 = Ib[4], c5 = Ib[5];
    const float* Xn = X + (size_t)n * (C_ * L_);
    const float* xp0 = Xn + c0 * L_;
    const float* xp1 = Xn + c1 * L_;
    const float* xp2 = Xn + c2 * L_;
    const float* xp3 = Xn + c3 * L_;
    const float* xp4 = Xn + c4 * L_;
    const float* xp5 = Xn + c5 * L_;

    // block-uniform weights -> SGPRs
    const float* Wb = W + (size_t)(comb * (K_ * H_) + h * K_) * KW_;
    float wr[K_ * KW_];
    #pragma unroll
    for (int q = 0; q < K_ * KW_; ++q) wr[q] = Wb[q];

    __syncthreads();   // zeros visible

    // ---- staging: two 3-channel bursts (24 in-flight loads each, VGPR-lean) ----
    {
        float ssum[8];
        {
            float l0[8], l1[8], l2[8];
            #pragma unroll
            for (int i = 0; i < 8; ++i) {
                const int t = tid + i * 256;
                l0[i] = xp0[t]; l1[i] = xp1[t]; l2[i] = xp2[t];
            }
            #pragma unroll
            for (int i = 0; i < 8; ++i)
                ssum[i] = (l0[i] + l1[i]) + l2[i];
        }
        {
            float l0[8], l1[8], l2[8];
            #pragma unroll
            for (int i = 0; i < 8; ++i) {
                const int t = tid + i * 256;
                l0[i] = xp3[t]; l1[i] = xp4[t]; l2[i] = xp5[t];
            }
            #pragma unroll
            for (int i = 0; i < 8; ++i) {
                const int t = tid + i * 256;
                s_buf[pad + t] = ssum[i] + ((l0[i] + l1[i]) + l2[i]);
            }
        }
    }
    __syncthreads();

    // ---- df=1: in-place diff pass, d[t] = S[t+1]-S[t] ----
    if (df == 1) {
        float dv[8];
        #pragma unroll
        for (int i = 0; i < 8; ++i) {
            const int t = tid + i * 256;
            dv[i] = s_buf[pad + t + 1] - s_buf[pad + t];   // pad+2048 is zero region
        }
        __syncthreads();
        #pragma unroll
        for (int i = 0; i < 8; ++i) {
            const int t = tid + i * 256;
            s_buf[pad + t] = (i == 7 && tid == 255) ? 0.0f : dv[i];  // t=2047 not in Lsrc
        }
        __syncthreads();
    }

    // ---- conv + equality-scatter (templated dilation) ----
    float cx[K_] = {0.f, 0.f, 0.f, 0.f, 0.f, 0.f, 0.f, 0.f};
    int   cn[K_] = {0, 0, 0, 0, 0, 0, 0, 0};

    switch (comb) {
        case  0: conv_phase<  1, false>(s_buf, wr, cx, cn, tid); break;
        case  1: conv_phase<  1, true >(s_buf, wr, cx, cn, tid); break;
        case  2: conv_phase<  2, false>(s_buf, wr, cx, cn, tid); break;
        case  3: conv_phase<  2, true >(s_buf, wr, cx, cn, tid); break;
        case  4: conv_phase<  4, false>(s_buf, wr, cx, cn, tid); break;
        case  5: conv_phase<  4, true >(s_buf, wr, cx, cn, tid); break;
        case  6: conv_phase<  8, false>(s_buf, wr, cx, cn, tid); break;
        case  7: conv_phase<  8, true >(s_buf, wr, cx, cn, tid); break;
        case  8: conv_phase< 16, false>(s_buf, wr, cx, cn, tid); break;
        case  9: conv_phase< 16, true >(s_buf, wr, cx, cn, tid); break;
        case 10: conv_phase< 32, false>(s_buf, wr, cx, cn, tid); break;
        case 11: conv_phase< 32, true >(s_buf, wr, cx, cn, tid); break;
        case 12: conv_phase< 64, false>(s_buf, wr, cx, cn, tid); break;
        case 13: conv_phase< 64, true >(s_buf, wr, cx, cn, tid); break;
        case 14: conv_phase<128, false>(s_buf, wr, cx, cn, tid); break;
        default: conv_phase<128, true >(s_buf, wr, cx, cn, tid); break;
    }

    __syncthreads();   // conv done reading s_buf

    // ---- conflict-free reduce matrix ----
    // accumulator r of source thread s lives at s_buf[(r*16 + (s>>4))*17 + (s&15)]
    {
        const int wc = tid >> 4;   // 0..15
        const int wu = tid & 15;   // 0..15
        #pragma unroll
        for (int k = 0; k < K_; ++k) {
            s_buf[((k     ) * 16 + wc) * 17 + wu] = cx[k];
            s_buf[((k + 8 ) * 16 + wc) * 17 + wu] = (float)cn[k];
        }
    }
    __syncthreads();

    {
        const int r = tid >> 4;    // accumulator id 0..15
        const int c = tid & 15;    // chunk id 0..15
        const int base = (r * 16 + c) * 17;
        float p = 0.f;
        #pragma unroll
        for (int u = 0; u < 16; ++u)
            p += s_buf[base + u];
        #pragma unroll
        for (int off = 1; off < 16; off <<= 1)
            p += __shfl_xor(p, off, 64);
        if (c == 0) {
            const int s = r >> 3;      // 0 = cmax, 1 = cmin
            const int k = r & 7;
            out[(size_t)n * FEAT_ + (comb * 2 + s) * (H_ * K_) + h * K_ + k] = p;
        }
    }
}

extern "C" void kernel_launch(void* const* d_in, const int* in_sizes, int n_in,
                              void* d_out, int out_size, void* d_ws, size_t ws_size,
                              hipStream_t stream) {
    const float* X = (const float*)d_in[0];
    const float* W = (const float*)d_in[1];
    const int*   I = (const int*)d_in[2];
    float* out = (float*)d_out;

    const int blocks = N_ * 16 * H_;   // 65536: (n, di, df, h)
    hipLaunchKernelGGL(hydra_kernel, dim3(blocks), dim3(256), 0, stream,
                       X, W, I, out);
}